// Round 10
// baseline (220.290 us; speedup 1.0000x reference)
//
#include <hip/hip_runtime.h>
#include <hip/hip_bf16.h>
#include <cstdint>

// bf16 fragments as 8 x short (4 VGPRs) per cdna_hip_programming.md §3
typedef __attribute__((ext_vector_type(8))) short bf16x8;
typedef __attribute__((ext_vector_type(4))) float f32x4;
typedef __attribute__((ext_vector_type(4))) uint16_t u16x4;

__device__ __forceinline__ uint16_t f2b(float f) {
  union { float f; uint32_t i; } v; v.f = f;
  return (uint16_t)((v.i + 0x7FFFu + ((v.i >> 16) & 1u)) >> 16);  // RNE
}

// async global->LDS, 16B per lane; LDS dest is wave-uniform base + lane*16
#define GLDS16(g, l) __builtin_amdgcn_global_load_lds( \
    (const __attribute__((address_space(1))) void*)(g), \
    (__attribute__((address_space(3))) void*)(l), 16, 0, 0)

// ---------------------------------------------------------------------------
// fp32 -> bf16 convert (RNE) for all three inputs in one launch
// ---------------------------------------------------------------------------
__global__ __launch_bounds__(256) void cvt_all(
    const float* __restrict__ x, const float* __restrict__ wa, const float* __restrict__ wp,
    uint16_t* __restrict__ xb, uint16_t* __restrict__ wab, uint16_t* __restrict__ wpb) {
  const int i = (blockIdx.x * 256 + threadIdx.x) * 4;
  const float* src; uint16_t* dst; int off;
  if (i < 4194304)      { src = x;  dst = xb;  off = i; }
  else if (i < 7340032) { src = wa; dst = wab; off = i - 4194304; }
  else                  { src = wp; dst = wpb; off = i - 7340032; }
  const float4 v = *(const float4*)(src + off);
  u16x4 o;
  o.x = f2b(v.x); o.y = f2b(v.y); o.z = f2b(v.z); o.w = f2b(v.w);
  *(u16x4*)(dst + off) = o;
}

// ---------------------------------------------------------------------------
// C[M,N] = A[M,K] @ B[N,K]^T + bias[N]. A,B bf16, bias fp32, fp32 accumulate.
// m97-proven BK=32 single-stage loop; BM x 128 tile, 4 waves of (BM/2) x 64.
// Vectorized epilogue via per-wave LDS transpose. (unchanged)
// ---------------------------------------------------------------------------
template <int BM, bool OUT_BF16>
__global__ __launch_bounds__(256) void gemm_bt_bias(
    const uint16_t* __restrict__ A, const uint16_t* __restrict__ B,
    const float* __restrict__ bias, void* __restrict__ Cv,
    int M, int N, int K) {
  constexpr int MI = BM / 32;
  constexpr int CHA = BM / 16;
  constexpr int CPW = (CHA + 8) / 4;
  constexpr size_t ST_BYTES = (size_t)(BM + 128) * 32 * 2;
  constexpr size_t CT_BYTES = OUT_BF16 ? (size_t)4 * (BM / 2) * 72 * 2
                                       : (size_t)4 * (BM / 2) * 68 * 4;
  constexpr size_t LB = CT_BYTES > ST_BYTES ? CT_BYTES : ST_BYTES;
  __shared__ alignas(16) unsigned char ldsb[LB];
  uint16_t* lds = (uint16_t*)ldsb;
  const int offB = BM * 32;

  const int tid = threadIdx.x;
  const int wave = tid >> 6, lane = tid & 63;
  const int q4 = lane >> 4, l16 = lane & 15;
  const int wm = wave >> 1, wn = wave & 1;
  const long blockM = (long)blockIdx.y * BM;
  const long blockN = (long)blockIdx.x * 128;

  f32x4 acc[MI][4] = {};

  for (int k0 = 0; k0 < K; k0 += 32) {
#pragma unroll
    for (int c = 0; c < CPW; ++c) {
      const int id = c * 4 + wave;
      const bool isB = id >= CHA;
      const int a = isB ? id - CHA : id;
      const uint16_t* mat = isB ? B : A;
      const long rowBase = isB ? blockN : blockM;
      const int off = isB ? offB : 0;
      const int flat = a * 64 + lane;
      const int row = flat >> 2, seg = flat & 3;
      GLDS16(mat + (rowBase + row) * (long)K + k0 + seg * 8, lds + off + a * 512);
    }
    __syncthreads();
    bf16x8 af[MI], bfr[4];
#pragma unroll
    for (int i = 0; i < MI; ++i)
      af[i] = *(const bf16x8*)&lds[(wm * (BM / 2) + i * 16 + l16) * 32 + q4 * 8];
#pragma unroll
    for (int j = 0; j < 4; ++j)
      bfr[j] = *(const bf16x8*)&lds[offB + (wn * 64 + j * 16 + l16) * 32 + q4 * 8];
#pragma unroll
    for (int i = 0; i < MI; ++i)
#pragma unroll
      for (int j = 0; j < 4; ++j)
        acc[i][j] = __builtin_amdgcn_mfma_f32_16x16x32_bf16(af[i], bfr[j], acc[i][j], 0, 0, 0);
    __syncthreads();
  }

  if (OUT_BF16) {
    uint16_t* ct = lds + wave * (BM / 2) * 72;
#pragma unroll
    for (int j = 0; j < 4; ++j) {
      const float bv = bias[blockN + wn * 64 + j * 16 + l16];
#pragma unroll
      for (int i = 0; i < MI; ++i)
#pragma unroll
        for (int r = 0; r < 4; ++r)
          ct[(i * 16 + q4 * 4 + r) * 72 + j * 16 + l16] = f2b(acc[i][j][r] + bv);
    }
    __syncthreads();
    uint16_t* Cb = (uint16_t*)Cv;
#pragma unroll
    for (int st = 0; st < BM / 16; ++st) {
      const int flat = st * 64 + lane;
      const int row = flat >> 3, seg = flat & 7;
      const bf16x8 v = *(const bf16x8*)&ct[row * 72 + seg * 8];
      *(bf16x8*)&Cb[(blockM + wm * (BM / 2) + row) * (long)N + blockN + wn * 64 + seg * 8] = v;
    }
  } else {
    float* ct = (float*)ldsb + wave * (BM / 2) * 68;
#pragma unroll
    for (int j = 0; j < 4; ++j) {
      const float bv = bias[blockN + wn * 64 + j * 16 + l16];
#pragma unroll
      for (int i = 0; i < MI; ++i)
#pragma unroll
        for (int r = 0; r < 4; ++r)
          ct[(i * 16 + q4 * 4 + r) * 68 + j * 16 + l16] = acc[i][j][r] + bv;
    }
    __syncthreads();
    float* Cb = (float*)Cv;
#pragma unroll
    for (int st = 0; st < BM / 8; ++st) {
      const int flat = st * 64 + lane;
      const int row = flat >> 4, seg = flat & 15;
      const f32x4 v = *(const f32x4*)&ct[row * 68 + seg * 4];
      *(f32x4*)&Cb[(blockM + wm * (BM / 2) + row) * (long)N + blockN + wn * 64 + seg * 4] = v;
    }
  }
}

// ---------------------------------------------------------------------------
// Flash-style causal attention, SPLIT-K across waves (round-9 bugfixed):
//  - Oex row stride fixed (256 floats, was 1024 -> OOB LDS writes)
//  - scores scaled by sc BEFORE masking with exact -1e30f; exp2(s - mnew)
//    (fmaf-rounding of mnew could produce +1e22 -> inf for fully-masked
//     waves, then inf*0 = NaN in the combine)
// ---------------------------------------------------------------------------
__global__ __launch_bounds__(256, 2) void attn_flash(
    const uint16_t* __restrict__ kqv, uint16_t* __restrict__ attn) {
  constexpr int T = 2048, C = 1024, C3 = 3072;
  __shared__ alignas(16) unsigned char mainb[65536];
  __shared__ alignas(16) float2 Sm[256];          // [ (w*4+ji)*16 + l16 ]
  uint16_t* Kt = (uint16_t*)mainb;                // [key][d] pitch 72
  uint16_t* Vt = (uint16_t*)(mainb + 18432);      // V^T [d][key'] pitch 136
  uint32_t* VtW = (uint32_t*)Vt;                  // pitch 68 dwords
  uint16_t* Pt = (uint16_t*)(mainb + 35840);      // 4 waves x [64 q][32 keys] pitch 36
  float*    Oex = (float*)mainb;                  // 4 x 4096 floats, lane-contiguous

  const int tid = threadIdx.x;
  const int wave = tid >> 6, lane = tid & 63;
  const int q4 = lane >> 4, l16 = lane & 15;
  const int p = blockIdx.x >> 5, bh = blockIdx.x & 31;
  const int b = bh >> 4, h = bh & 15;
  const size_t base = (size_t)b * T * C3;
  const size_t obase = (size_t)b * T * C;
  const int hD = h * 64;
  const float sc = 0.125f * 1.4426950408889634f;  // D^-0.5 * log2(e)

  const int qb0 = 31 - p, qb1 = p;
  const int nkt0 = (qb0 >> 1) + 1;
  const int tr = tid >> 3, kch = tid & 7;         // staging coords
  const int wkb = wave * 32;                      // wave's key base within tile
  uint16_t* Pw = Pt + wave * 2304;                // 64 * 36

  int qb = qb0;
  bf16x8 qf[4][2];
#pragma unroll
  for (int ji = 0; ji < 4; ++ji) {
    const size_t qoff = base + (size_t)(qb * 64 + ji * 16 + l16) * C3 + C + hD + q4 * 8;
    qf[ji][0] = *(const bf16x8*)&kqv[qoff];
    qf[ji][1] = *(const bf16x8*)&kqv[qoff + 32];
  }

  f32x4 o[4][4] = {};                             // O_partial[q=ji*16+q4*4+r][d=dg*16+l16]
  float m_i[4] = {-1e30f, -1e30f, -1e30f, -1e30f};
  float l_i[4] = {0.f, 0.f, 0.f, 0.f};
  int kt = 0;
  bool ss1 = false;

  // prefetch tile 0 (keys 0..127 — identical for every strip)
  bf16x8 pk[4], pv[2][2];
#pragma unroll
  for (int rr = 0; rr < 4; ++rr)
    pk[rr] = *(const bf16x8*)&kqv[base + (size_t)(rr * 32 + tr) * C3 + hD + kch * 8];
#pragma unroll
  for (int s2 = 0; s2 < 2; ++s2) {
    const size_t g = base + (size_t)(2 * (s2 * 32 + tr)) * C3 + 2 * C + hD + kch * 8;
    pv[s2][0] = *(const bf16x8*)&kqv[g];
    pv[s2][1] = *(const bf16x8*)&kqv[g + C3];
  }

  for (int t = 0; t < 17; ++t) {
    const int kbase = kt * 128;
    const bool lastOfStrip = !ss1 ? (kt == nkt0 - 1) : (t == 16);

    __syncthreads();   // A: prev-tile LDS reads (or prev-strip Oex reads) done
    // --- stage K(t) ---
#pragma unroll
    for (int rr = 0; rr < 4; ++rr)
      *(bf16x8*)&Kt[(rr * 32 + tr) * 72 + kch * 8] = pk[rr];
    // --- stage V(t): v_perm pack key-pairs, rot-16 swizzle ---
#pragma unroll
    for (int s2 = 0; s2 < 2; ++s2) {
      const int colw = ((s2 * 32 + tr) + 8 * kch) & 63;
      const uint32_t* a0 = (const uint32_t*)&pv[s2][0];
      const uint32_t* a1 = (const uint32_t*)&pv[s2][1];
#pragma unroll
      for (int i = 0; i < 8; ++i) {
        const uint32_t w = (i & 1)
            ? __builtin_amdgcn_perm(a1[i >> 1], a0[i >> 1], 0x07060302u)
            : __builtin_amdgcn_perm(a1[i >> 1], a0[i >> 1], 0x05040100u);
        VtW[(kch * 8 + i) * 68 + colw] = w;
      }
    }
    __syncthreads();   // B: staging visible; no loads outstanding
    // --- prefetch tile t+1 ---
    if (t < 16) {
      const int kb2 = (lastOfStrip ? 0 : kt + 1) * 128;
#pragma unroll
      for (int rr = 0; rr < 4; ++rr)
        pk[rr] = *(const bf16x8*)&kqv[base + (size_t)(kb2 + rr * 32 + tr) * C3 + hD + kch * 8];
#pragma unroll
      for (int s2 = 0; s2 < 2; ++s2) {
        const size_t g = base + (size_t)(kb2 + 2 * (s2 * 32 + tr)) * C3 + 2 * C + hD + kch * 8;
        pv[s2][0] = *(const bf16x8*)&kqv[g];
        pv[s2][1] = *(const bf16x8*)&kqv[g + C3];
      }
    }
    // --- QK(t): S^T[key in wave's 32][q in 64] ---
    bf16x8 kf[2][2];
#pragma unroll
    for (int kg = 0; kg < 2; ++kg) {
      const uint16_t* kr = &Kt[(wkb + kg * 16 + l16) * 72 + q4 * 8];
      kf[kg][0] = *(const bf16x8*)kr;
      kf[kg][1] = *(const bf16x8*)(kr + 32);
    }
    f32x4 sv[2][4];
#pragma unroll
    for (int kg = 0; kg < 2; ++kg)
#pragma unroll
      for (int ji = 0; ji < 4; ++ji) {
        f32x4 z = {};
        z = __builtin_amdgcn_mfma_f32_16x16x32_bf16(kf[kg][0], qf[ji][0], z, 0, 0, 0);
        z = __builtin_amdgcn_mfma_f32_16x16x32_bf16(kf[kg][1], qf[ji][1], z, 0, 0, 0);
        sv[kg][ji] = z;
      }
    // --- scale FIRST, then mask with exact -1e30 (NaN-safe for masked waves) ---
#pragma unroll
    for (int kg = 0; kg < 2; ++kg)
#pragma unroll
      for (int ji = 0; ji < 4; ++ji)
#pragma unroll
        for (int r = 0; r < 4; ++r) sv[kg][ji][r] *= sc;
    if (kbase + 127 > qb * 64) {
#pragma unroll
      for (int kg = 0; kg < 2; ++kg) {
        const int key0 = kbase + wkb + kg * 16 + q4 * 4;
#pragma unroll
        for (int ji = 0; ji < 4; ++ji) {
          const int qv = qb * 64 + ji * 16 + l16;
#pragma unroll
          for (int r = 0; r < 4; ++r)
            sv[kg][ji][r] = (key0 + r <= qv) ? sv[kg][ji][r] : -1e30f;
        }
      }
    }
    // --- online softmax per ji (wave-local over its 32 keys) ---
    float alpha[4];
    bool mchg = false;
#pragma unroll
    for (int ji = 0; ji < 4; ++ji) {
      float mloc = sv[0][ji][0];
#pragma unroll
      for (int kg = 0; kg < 2; ++kg)
#pragma unroll
        for (int r = 0; r < 4; ++r) mloc = fmaxf(mloc, sv[kg][ji][r]);
      mloc = fmaxf(mloc, __shfl_xor(mloc, 16, 64));
      mloc = fmaxf(mloc, __shfl_xor(mloc, 32, 64));
      const float mnew = fmaxf(m_i[ji], mloc);
      alpha[ji] = exp2f(m_i[ji] - mnew);
      mchg = mchg || (mnew > m_i[ji]);
      m_i[ji] = mnew;
      float rs = 0.f;
#pragma unroll
      for (int kg = 0; kg < 2; ++kg)
#pragma unroll
        for (int r = 0; r < 4; ++r) {
          const float pe = exp2f(sv[kg][ji][r] - mnew);
          sv[kg][ji][r] = pe;
          rs += pe;
        }
      rs += __shfl_xor(rs, 16, 64);
      rs += __shfl_xor(rs, 32, 64);
      l_i[ji] = l_i[ji] * alpha[ji] + rs;
    }
    if (__any(mchg)) {
#pragma unroll
      for (int ji = 0; ji < 4; ++ji)
#pragma unroll
        for (int r = 0; r < 4; ++r) {
          const float ar = __shfl(alpha[ji], q4 * 4 + r, 64);
#pragma unroll
          for (int dg = 0; dg < 4; ++dg) o[ji][dg][r] *= ar;
        }
    }
    // --- P write (wave-private region) ---
#pragma unroll
    for (int kg = 0; kg < 2; ++kg)
#pragma unroll
      for (int ji = 0; ji < 4; ++ji) {
        union { __hip_bfloat162 h2; uint32_t u; } c01, c23;
        c01.h2 = __float22bfloat162_rn(make_float2(sv[kg][ji][0], sv[kg][ji][1]));
        c23.h2 = __float22bfloat162_rn(make_float2(sv[kg][ji][2], sv[kg][ji][3]));
        uint2 pkw; pkw.x = c01.u; pkw.y = c23.u;
        *(uint2*)&Pw[(ji * 16 + l16) * 36 + kg * 16 + q4 * 4] = pkw;
      }
    // --- O += P·V over the wave's 32 keys ---
    bf16x8 pf[4];
#pragma unroll
    for (int ji = 0; ji < 4; ++ji)
      pf[ji] = *(const bf16x8*)&Pw[(ji * 16 + l16) * 36 + q4 * 8];
#pragma unroll
    for (int dg = 0; dg < 4; ++dg) {
      const int d = dg * 16 + l16;
      const int col = (wkb + q4 * 8 + 16 * (d >> 3)) & 127;
      const bf16x8 vf = *(const bf16x8*)&Vt[d * 136 + col];
#pragma unroll
      for (int ji = 0; ji < 4; ++ji)
        o[ji][dg] = __builtin_amdgcn_mfma_f32_16x16x32_bf16(pf[ji], vf, o[ji][dg], 0, 0, 0);
    }
    // --- strip boundary: cross-wave split-K combine + output ---
    if (lastOfStrip) {
      if (q4 == 0) {
#pragma unroll
        for (int ji = 0; ji < 4; ++ji)
          Sm[(wave * 4 + ji) * 16 + l16] = make_float2(m_i[ji], l_i[ji]);
      }
      __syncthreads();   // C: stats visible; all PV reads of Vt/Pt done
      float Lg[4], bown[4];
#pragma unroll
      for (int ji = 0; ji < 4; ++ji) {
        const float2 s0 = Sm[(0 * 4 + ji) * 16 + l16];
        const float2 s1 = Sm[(1 * 4 + ji) * 16 + l16];
        const float2 s2 = Sm[(2 * 4 + ji) * 16 + l16];
        const float2 s3 = Sm[(3 * 4 + ji) * 16 + l16];
        const float M = fmaxf(fmaxf(s0.x, s1.x), fmaxf(s2.x, s3.x));
        Lg[ji] = s0.y * exp2f(s0.x - M) + s1.y * exp2f(s1.x - M) +
                 s2.y * exp2f(s2.x - M) + s3.y * exp2f(s3.x - M);
        bown[ji] = exp2f(m_i[ji] - M);
      }
      // write scaled O-partials: per-wave 16 rows x 256 floats, lane-contiguous
      float* myO = Oex + wave * 4096;
#pragma unroll
      for (int ji = 0; ji < 4; ++ji) {
        float br[4];
#pragma unroll
        for (int r = 0; r < 4; ++r) br[r] = __shfl(bown[ji], q4 * 4 + r, 64);
#pragma unroll
        for (int dg = 0; dg < 4; ++dg) {
          f32x4 tmp;
#pragma unroll
          for (int r = 0; r < 4; ++r) tmp[r] = o[ji][dg][r] * br[r];
          *(f32x4*)&myO[(ji * 4 + dg) * 256 + lane * 4] = tmp;
        }
      }
      __syncthreads();   // D: Oex visible
      float Lr[4];
#pragma unroll
      for (int r = 0; r < 4; ++r)
        Lr[r] = 1.0f / __shfl(Lg[wave], q4 * 4 + r, 64);
#pragma unroll
      for (int dg = 0; dg < 4; ++dg) {
        f32x4 acc = *(const f32x4*)&Oex[0 * 4096 + (wave * 4 + dg) * 256 + lane * 4];
#pragma unroll
        for (int w2 = 1; w2 < 4; ++w2) {
          const f32x4 t2 = *(const f32x4*)&Oex[w2 * 4096 + (wave * 4 + dg) * 256 + lane * 4];
#pragma unroll
          for (int r = 0; r < 4; ++r) acc[r] += t2[r];
        }
#pragma unroll
        for (int r = 0; r < 4; ++r) {
          const int q = qb * 64 + wave * 16 + q4 * 4 + r;
          attn[obase + (size_t)q * C + hD + dg * 16 + l16] = f2b(acc[r] * Lr[r]);
        }
      }
      if (!ss1) {
        ss1 = true;
        qb = qb1;
#pragma unroll
        for (int ji = 0; ji < 4; ++ji) {
          const size_t qoff = base + (size_t)(qb * 64 + ji * 16 + l16) * C3 + C + hD + q4 * 8;
          qf[ji][0] = *(const bf16x8*)&kqv[qoff];
          qf[ji][1] = *(const bf16x8*)&kqv[qoff + 32];
          m_i[ji] = -1e30f; l_i[ji] = 0.f;
#pragma unroll
          for (int dg = 0; dg < 4; ++dg) o[ji][dg] = (f32x4){0.f, 0.f, 0.f, 0.f};
        }
        kt = 0;
      }
    } else {
      ++kt;
    }
  }
}

extern "C" void kernel_launch(void* const* d_in, const int* in_sizes, int n_in,
                              void* d_out, int out_size, void* d_ws, size_t ws_size,
                              hipStream_t stream) {
  const float* x      = (const float*)d_in[0];  // (2,2048,1024) fp32
  const float* w_attn = (const float*)d_in[1];  // (3072,1024)  fp32
  const float* b_attn = (const float*)d_in[2];  // (3072,)      fp32
  const float* w_proj = (const float*)d_in[3];  // (1024,1024)  fp32
  const float* b_proj = (const float*)d_in[4];  // (1024,)      fp32
  float* out = (float*)d_out;                   // (2,2048,1024) fp32

  // ws layout (bf16): xb | wab | wpb | kqv | attnb
  uint16_t* xb    = (uint16_t*)d_ws;                     // 4096*1024
  uint16_t* wab   = xb  + (size_t)4096 * 1024;           // 3072*1024
  uint16_t* wpb   = wab + (size_t)3072 * 1024;           // 1024*1024
  uint16_t* kqv   = wpb + (size_t)1024 * 1024;           // 4096*3072
  uint16_t* attnb = kqv + (size_t)4096 * 3072;           // 4096*1024

  dim3 blk(256, 1, 1);
  hipLaunchKernelGGL(cvt_all, dim3(8192), blk, 0, stream, x, w_attn, w_proj, xb, wab, wpb);

  hipLaunchKernelGGL((gemm_bt_bias<128, true>), dim3(3072 / 128, 4096 / 128, 1), blk, 0, stream,
                     xb, wab, b_attn, (void*)kqv, 4096, 3072, 1024);
  hipLaunchKernelGGL(attn_flash, dim3(512, 1, 1), blk, 0, stream, kqv, attnb);
  hipLaunchKernelGGL((gemm_bt_bias<64, false>), dim3(1024 / 128, 4096 / 64, 1), blk, 0, stream,
                     attnb, wpb, b_proj, (void*)out, 4096, 1024, 1024);
}